// Round 3
// baseline (885.024 us; speedup 1.0000x reference)
//
#include <hip/hip_runtime.h>
#include <hip/hip_bf16.h>
#include <cstdint>
#include <cstddef>

typedef __bf16 bf16_t;
typedef __attribute__((ext_vector_type(8))) bf16_t bf16x8;
typedef __attribute__((ext_vector_type(4))) float f32x4;

#define B_   16
#define SDEC 64
#define SENC 128
#define H_   1024
#define E_   512
#define V_   32000

// async global->LDS, 16B per lane. LDS dest = wave-uniform base + lane*16.
__device__ __forceinline__ void gload_lds16(const void* g, void* l) {
  __builtin_amdgcn_global_load_lds(
      (const __attribute__((address_space(1))) unsigned int*)g,
      (__attribute__((address_space(3))) unsigned int*)l, 16, 0, 0);
}

// ---------------------------------------------------------------------------
// f32 -> bf16 cast, 8 elems/thread.
// ---------------------------------------------------------------------------
__global__ __launch_bounds__(256)
void cvt_bf16(const float* __restrict__ s, bf16_t* __restrict__ d, int n8)
{
  const int i = blockIdx.x * 256 + threadIdx.x;
  if (i >= n8) return;
  const f32x4* sp = (const f32x4*)s + (size_t)i * 2;
  f32x4 a = sp[0], b = sp[1];
  union { bf16_t h[8]; uint4 u; } p;
  p.h[0] = (bf16_t)a[0]; p.h[1] = (bf16_t)a[1];
  p.h[2] = (bf16_t)a[2]; p.h[3] = (bf16_t)a[3];
  p.h[4] = (bf16_t)b[0]; p.h[5] = (bf16_t)b[1];
  p.h[6] = (bf16_t)b[2]; p.h[7] = (bf16_t)b[3];
  *(uint4*)(d + (size_t)i * 8) = p.u;
}

// ---------------------------------------------------------------------------
// m97-structure bf16 GEMM: C[M,N] = A[M,K] @ W[N,K]^T (+bias), f32 out.
// A, W bf16 row-major. 128x128 tile, BK=64, 4 waves (2x2),
// global_load_lds width-16 staging into LINEAR LDS, 16x16x32 bf16 MFMA.
// Requires M%128==0, N%128==0, K%64==0, grid=(M/128, N/128), nwg%8==0.
// MODE 0: C[m*N+n]   MODE 1: m=s*16+b -> C[(b*64+s)*V_+n]
// ---------------------------------------------------------------------------
template<int MODE>
__global__ __launch_bounds__(256)
void gemm_b16(const bf16_t* __restrict__ A, const bf16_t* __restrict__ W,
              const float* __restrict__ bias, float* __restrict__ C,
              int M, int N, int K)
{
  __shared__ __align__(16) char lsA[128 * 128];  // 128 rows x 64 bf16
  __shared__ __align__(16) char lsB[128 * 128];

  const int t = threadIdx.x, lane = t & 63, wid = t >> 6;
  const int wr = wid >> 1, wc = wid & 1;

  const int nwg = gridDim.x * gridDim.y;
  const int dd  = blockIdx.y * gridDim.x + blockIdx.x;
  const int qq  = nwg >> 3;
  const int lid = (dd & 7) * qq + (dd >> 3);
  const int mt  = lid % gridDim.x;      // m fastest -> W n-panel stays in L2
  const int nt  = lid / gridDim.x;
  const int m0 = mt * 128, n0 = nt * 128;

  // staging: wave wid owns tile rows [wid*32, wid*32+32); per instruction,
  // lane l -> row +(l>>3), 16B chunk (l&7); 4 insts/operand cover 32 rows.
  const int srow = wid * 32 + (lane >> 3);
  const int scol = (lane & 7) * 8;               // bf16 elems
  const bf16_t* agp = A + (size_t)(m0 + srow) * K + scol;
  const bf16_t* wgp = W + (size_t)(n0 + srow) * K + scol;
  char* alds = lsA + wid * 32 * 128;
  char* wlds = lsB + wid * 32 * 128;

  f32x4 acc[4][4] = {};

  for (int k0 = 0; k0 < K; k0 += 64) {
#pragma unroll
    for (int i = 0; i < 4; ++i)
      gload_lds16(agp + (size_t)(i * 8) * K + k0, alds + i * 1024);
#pragma unroll
    for (int i = 0; i < 4; ++i)
      gload_lds16(wgp + (size_t)(i * 8) * K + k0, wlds + i * 1024);
    __syncthreads();

#pragma unroll
    for (int kk = 0; kk < 2; ++kk) {
      bf16x8 af[4], bfr[4];
      const int cb = kk * 64 + ((lane >> 4) << 4);
#pragma unroll
      for (int mi = 0; mi < 4; ++mi)
        af[mi] = *(const bf16x8*)(lsA + (wr * 64 + mi * 16 + (lane & 15)) * 128 + cb);
#pragma unroll
      for (int ni = 0; ni < 4; ++ni)
        bfr[ni] = *(const bf16x8*)(lsB + (wc * 64 + ni * 16 + (lane & 15)) * 128 + cb);
#pragma unroll
      for (int mi = 0; mi < 4; ++mi)
#pragma unroll
        for (int ni = 0; ni < 4; ++ni)
          acc[mi][ni] = __builtin_amdgcn_mfma_f32_16x16x32_bf16(
              af[mi], bfr[ni], acc[mi][ni], 0, 0, 0);
    }
    __syncthreads();
  }

  // C/D layout: col=lane&15, row=(lane>>4)*4+j
#pragma unroll
  for (int mi = 0; mi < 4; ++mi) {
#pragma unroll
    for (int ni = 0; ni < 4; ++ni) {
      const int n = n0 + wc * 64 + ni * 16 + (lane & 15);
      const float bv = bias ? bias[n] : 0.f;
#pragma unroll
      for (int j = 0; j < 4; ++j) {
        const int m = m0 + wr * 64 + mi * 16 + ((lane >> 4) << 2) + j;
        const float v = acc[mi][ni][j] + bv;
        if (MODE == 0) {
          C[(size_t)m * N + n] = v;
        } else {
          const int s = m >> 4, b = m & 15;
          C[((size_t)b * SDEC + s) * V_ + n] = v;
        }
      }
    }
  }
}

// ---------------------------------------------------------------------------
// f32-staged fallback GEMM (in-flight bf16 convert, swizzled LDS).
// ---------------------------------------------------------------------------
template<int MODE>
__global__ __launch_bounds__(256)
void gemm_f32(const float* __restrict__ A, const float* __restrict__ W,
              const float* __restrict__ bias, float* __restrict__ C,
              int M, int N, int K)
{
  __shared__ __align__(16) char lsA[128 * 128];
  __shared__ __align__(16) char lsB[128 * 128];

  const int t = threadIdx.x, lane = t & 63, wid = t >> 6;
  const int wr = wid >> 1, wc = wid & 1;

  const int nwg = gridDim.x * gridDim.y;
  const int dd  = blockIdx.y * gridDim.x + blockIdx.x;
  const int qq  = nwg >> 3;
  const int lid = (dd & 7) * qq + (dd >> 3);
  const int mt  = lid % gridDim.x;
  const int nt  = lid / gridDim.x;
  const int m0 = mt * 128, n0 = nt * 128;

  const int rg = t >> 4, c4 = t & 15;
  f32x4 acc[4][4] = {};

  for (int k0 = 0; k0 < K; k0 += 64) {
    const float* ap = A + (size_t)(m0 + rg * 8) * K + k0 + c4 * 4;
    const float* bp = W + (size_t)(n0 + rg * 8) * K + k0 + c4 * 4;
#pragma unroll
    for (int i = 0; i < 8; ++i) {
      f32x4 va = *(const f32x4*)(ap + (size_t)i * K);
      f32x4 vb = *(const f32x4*)(bp + (size_t)i * K);
      const int row  = rg * 8 + i;
      const int boff = row * 128 + ((c4 * 8) ^ ((row & 7) << 4));
      union { bf16_t h[4]; uint2 u; } pa, pb;
      pa.h[0] = (bf16_t)va[0]; pa.h[1] = (bf16_t)va[1];
      pa.h[2] = (bf16_t)va[2]; pa.h[3] = (bf16_t)va[3];
      pb.h[0] = (bf16_t)vb[0]; pb.h[1] = (bf16_t)vb[1];
      pb.h[2] = (bf16_t)vb[2]; pb.h[3] = (bf16_t)vb[3];
      *(uint2*)(lsA + boff) = pa.u;
      *(uint2*)(lsB + boff) = pb.u;
    }
    __syncthreads();
#pragma unroll
    for (int kk = 0; kk < 2; ++kk) {
      bf16x8 af[4], bfr[4];
#pragma unroll
      for (int mi = 0; mi < 4; ++mi) {
        const int r  = wr * 64 + mi * 16 + (lane & 15);
        const int bc = (kk * 64 + ((lane >> 4) << 4)) ^ ((r & 7) << 4);
        af[mi] = *(const bf16x8*)(lsA + r * 128 + bc);
      }
#pragma unroll
      for (int ni = 0; ni < 4; ++ni) {
        const int r  = wc * 64 + ni * 16 + (lane & 15);
        const int bc = (kk * 64 + ((lane >> 4) << 4)) ^ ((r & 7) << 4);
        bfr[ni] = *(const bf16x8*)(lsB + r * 128 + bc);
      }
#pragma unroll
      for (int mi = 0; mi < 4; ++mi)
#pragma unroll
        for (int ni = 0; ni < 4; ++ni)
          acc[mi][ni] = __builtin_amdgcn_mfma_f32_16x16x32_bf16(
              af[mi], bfr[ni], acc[mi][ni], 0, 0, 0);
    }
    __syncthreads();
  }

#pragma unroll
  for (int mi = 0; mi < 4; ++mi) {
#pragma unroll
    for (int ni = 0; ni < 4; ++ni) {
      const int n = n0 + wc * 64 + ni * 16 + (lane & 15);
      const float bv = bias ? bias[n] : 0.f;
#pragma unroll
      for (int j = 0; j < 4; ++j) {
        const int m = m0 + wr * 64 + mi * 16 + ((lane >> 4) << 2) + j;
        const float v = acc[mi][ni][j] + bv;
        if (MODE == 0) {
          C[(size_t)m * N + n] = v;
        } else {
          const int s = m >> 4, b = m & 15;
          C[((size_t)b * SDEC + s) * V_ + n] = v;
        }
      }
    }
  }
}

// ---------------------------------------------------------------------------
// Small-M GEMM: out[16,N] = X[16,K] @ W[N,K]^T (+bias). One wave per n, K=1024.
// ---------------------------------------------------------------------------
__global__ __launch_bounds__(256)
void small_bt(const float* __restrict__ X, const float* __restrict__ W,
              const float* __restrict__ bias, float* __restrict__ out,
              int N, int K)
{
  __shared__ float xs[16 * 1024];
  const int t = threadIdx.x;
  const int nv = 16 * K / 4;
  for (int i = t; i < nv; i += 256)
    ((f32x4*)xs)[i] = ((const f32x4*)X)[i];
  __syncthreads();

  const int lane = t & 63;
  const int n = blockIdx.x * 4 + (t >> 6);
  float acc[16];
#pragma unroll
  for (int b = 0; b < 16; ++b) acc[b] = 0.f;
  const float* wrow = W + (size_t)n * K;
  for (int kc = 0; kc < K; kc += 64) {
    const float wv_ = wrow[kc + lane];
#pragma unroll
    for (int b = 0; b < 16; ++b)
      acc[b] += xs[b * K + kc + lane] * wv_;
  }
  const float bv = bias ? bias[n] : 0.f;
#pragma unroll
  for (int b = 0; b < 16; ++b) {
    float v = acc[b];
#pragma unroll
    for (int o = 32; o; o >>= 1) v += __shfl_xor(v, o);
    if (lane == b) out[(size_t)b * N + n] = v + bv;
  }
}

// ---------------------------------------------------------------------------
// Additive attention: scores=tanh(q+k)@wv, mask, softmax, context=attn@enc.
// ---------------------------------------------------------------------------
__global__ __launch_bounds__(256)
void attn_ctx(const float* __restrict__ q, const float* __restrict__ kproj,
              const float* __restrict__ wv, const int* __restrict__ vlens,
              const float* __restrict__ enc, float* __restrict__ context)
{
  __shared__ float qs[1024], wvs[1024], sc[128];
  const int b = blockIdx.x;
  const int t = threadIdx.x;
  for (int i = t; i < 1024; i += 256) { qs[i] = q[b * 1024 + i]; wvs[i] = wv[i]; }
  __syncthreads();

  const int lane = t & 63, wid = t >> 6;
  const int len = vlens[b];
  for (int s = wid; s < 128; s += 4) {
    const float* kp = kproj + ((size_t)b * 128 + s) * 1024;
    float a = 0.f;
    for (int h = lane; h < 1024; h += 64)
      a += tanhf(qs[h] + kp[h]) * wvs[h];
#pragma unroll
    for (int o = 32; o; o >>= 1) a += __shfl_xor(a, o);
    if (lane == 0) sc[s] = (s < len) ? a : -1e6f;
  }
  __syncthreads();

  if (wid == 0) {
    float s0 = sc[lane], s1 = sc[lane + 64];
    float m = fmaxf(s0, s1);
#pragma unroll
    for (int o = 32; o; o >>= 1) m = fmaxf(m, __shfl_xor(m, o));
    float e0 = expf(s0 - m), e1 = expf(s1 - m);
    float sum = e0 + e1;
#pragma unroll
    for (int o = 32; o; o >>= 1) sum += __shfl_xor(sum, o);
    const float inv = 1.f / sum;
    sc[lane] = e0 * inv; sc[lane + 64] = e1 * inv;
  }
  __syncthreads();

  for (int h = t; h < 1024; h += 256) {
    float a = 0.f;
    const float* ep = enc + (size_t)b * 128 * 1024 + h;
#pragma unroll 8
    for (int s = 0; s < 128; ++s)
      a += sc[s] * ep[(size_t)s * 1024];
    context[b * 1024 + h] = a;
  }
}

// x0[m,0:1024]=context[b], x0[m,1024:1536]=emb[inputs[b,s]]  (m = s*16+b)
__global__ __launch_bounds__(256)
void build_x0(const float* __restrict__ context, const float* __restrict__ emb,
              const int* __restrict__ inputs, float* __restrict__ x0f,
              bf16_t* __restrict__ x0b)
{
  const int m = blockIdx.x;
  const int b = m & 15, s = m >> 4;
  const int t = threadIdx.x;
  float* xr = x0f + (size_t)m * 1536;
  bf16_t* xb = x0b ? x0b + (size_t)m * 1536 : nullptr;
  const float* er = emb + (size_t)inputs[b * 64 + s] * 512;
  for (int j = t; j < 1024; j += 256) {
    const float v = context[b * 1024 + j];
    xr[j] = v; if (xb) xb[j] = (bf16_t)v;
  }
  for (int j = t; j < 512; j += 256) {
    const float v = er[j];
    xr[1024 + j] = v; if (xb) xb[1024 + j] = (bf16_t)v;
  }
}

// GRU gate combine -> hout (f32) and optional bf16 copy for the next GEMM.
__global__ __launch_bounds__(256)
void gru_combine(const float* __restrict__ gi, const float* __restrict__ gh,
                 const float* __restrict__ hprev, float* __restrict__ hout,
                 bf16_t* __restrict__ houtb)
{
  const int idx = blockIdx.x * 256 + threadIdx.x;
  const int m = idx >> 10, j = idx & 1023, b = m & 15;
  const float* gim = gi + (size_t)m * 3072;
  const float* ghb = gh + (size_t)b * 3072;
  const float ir = gim[j], iz = gim[1024 + j], in_ = gim[2048 + j];
  const float hr = ghb[j], hz = ghb[1024 + j], hn = ghb[2048 + j];
  const float r = 1.f / (1.f + expf(-(ir + hr)));
  const float z = 1.f / (1.f + expf(-(iz + hz)));
  const float n = tanhf(in_ + r * hn);
  const float v = (1.f - z) * n + z * hprev[b * 1024 + j];
  hout[idx] = v;
  if (houtb) houtb[idx] = (bf16_t)v;
}

// decoder_hidden = stack([h1[step 63], h2[step 63]]) -> out tail.
// MUST run before the logits GEMM (h1 lives in the logits scratch region).
__global__ __launch_bounds__(256)
void write_dh(const float* __restrict__ h1, const float* __restrict__ h2,
              float* __restrict__ out)
{
  const int idx = blockIdx.x * 256 + threadIdx.x;  // 0..32767
  const int l = idx >> 14;
  const int b = (idx >> 10) & 15;
  const int h = idx & 1023;
  const float* src = l ? h2 : h1;
  out[(size_t)B_ * SDEC * V_ + idx] = src[(size_t)(63 * 16 + b) * 1024 + h];
}

// ---------------------------------------------------------------------------
extern "C" void kernel_launch(void* const* d_in, const int* in_sizes, int n_in,
                              void* d_out, int out_size, void* d_ws, size_t ws_size,
                              hipStream_t stream)
{
  const int*   inputs = (const int*)  d_in[0];
  const float* enc    = (const float*)d_in[1];
  const float* ehs    = (const float*)d_in[2];
  const int*   vlens  = (const int*)  d_in[3];
  const float* emb    = (const float*)d_in[4];
  const float* Wq     = (const float*)d_in[5];
  const float* Wk     = (const float*)d_in[6];
  const float* wv     = (const float*)d_in[7];
  const float* W_ih0  = (const float*)d_in[8];
  const float* W_hh0  = (const float*)d_in[9];
  const float* b_ih0  = (const float*)d_in[10];
  const float* b_hh0  = (const float*)d_in[11];
  const float* W_ih1  = (const float*)d_in[12];
  const float* W_hh1  = (const float*)d_in[13];
  const float* b_ih1  = (const float*)d_in[14];
  const float* b_hh1  = (const float*)d_in[15];
  const float* fc_w   = (const float*)d_in[16];
  const float* fc_b   = (const float*)d_in[17];
  float* out = (float*)d_out;

  // ---- scratch arena #1: the logits region of d_out (131 MB, re-poisoned
  // each launch; everything here is dead before the logits GEMM overwrites
  // it). Offsets in f32 units; total used 7,208,960 << 32,768,000. ----
  float*  kgi  = out;                        // 3,145,728 (kproj / gi)
  float*  x0f  = out + 3145728;              // 1,572,864
  bf16_t* x0b  = (bf16_t*)(out + 4718592);   //   786,432 f32 slots
  float*  h1   = out + 5505024;              // 1,048,576
  bf16_t* h1b  = (bf16_t*)(out + 6553600);   //   524,288 f32 slots
  float*  q_   = out + 7077888;              //    16,384
  float*  ctx  = out + 7094272;              //    16,384
  float*  gh0  = out + 7110656;              //    49,152
  float*  gh1  = out + 7159808;              //    49,152

  // ---- scratch arena #2: d_ws, tier-guarded. Only h2 (4 MB) is required:
  // it is the A operand of the logits GEMM and must survive the C-write. ----
  float*  ws    = (float*)d_ws;
  float*  h2    = ws;                        // 1,048,576 f32 = 4 MB (required)
  bf16_t* h2b   = (bf16_t*)(ws + 1048576);   // 524,288 f32 slots
  bf16_t* encb  = (bf16_t*)(ws + 1572864);   // 1,048,576 f32 slots
  bf16_t* Wkb   = (bf16_t*)(ws + 2621440);   //   524,288
  bf16_t* Wih0b = (bf16_t*)(ws + 3145728);   // 2,359,296
  bf16_t* Wih1b = (bf16_t*)(ws + 5505024);   // 1,572,864 -> t2 end 7,077,888
  bf16_t* fcwb  = (bf16_t*)(ws + 7077888);   // 16,384,000 -> t1 end 23,461,888

  const bool hb = ws_size >= (size_t)1572864  * 4;  // 6.3 MB: h2b available
  const bool t2 = ws_size >= (size_t)7077888  * 4;  // 28.3 MB: small weights bf16
  const bool t1 = ws_size >= (size_t)23461888 * 4 && hb;  // 93.8 MB: + fc_w bf16

  const float* ehs0 = ehs;
  const float* ehs1 = ehs + 16 * 1024;

  // weight conversions (tier-guarded, all into d_ws)
  if (t2) {
    cvt_bf16<<<512,  256, 0, stream>>>(Wk,    Wkb,   1048576 / 8);
    cvt_bf16<<<2304, 256, 0, stream>>>(W_ih0, Wih0b, 4718592 / 8);
    cvt_bf16<<<1536, 256, 0, stream>>>(W_ih1, Wih1b, 3145728 / 8);
    cvt_bf16<<<1024, 256, 0, stream>>>(enc,   encb,  2097152 / 8);
  }
  if (t1)
    cvt_bf16<<<16000, 256, 0, stream>>>(fc_w, fcwb, 32768000 / 8);

  // q = ehs[1] @ Wq.T ; gh_l = ehs[l] @ W_hh_l.T + b_hh_l
  small_bt<<<256, 256, 0, stream>>>(ehs1, Wq, nullptr, q_, 1024, 1024);
  small_bt<<<768, 256, 0, stream>>>(ehs0, W_hh0, b_hh0, gh0, 3072, 1024);
  small_bt<<<768, 256, 0, stream>>>(ehs1, W_hh1, b_hh1, gh1, 3072, 1024);

  // kproj = enc @ Wk.T  [2048,1024]
  if (t2) gemm_b16<0><<<dim3(16, 8), 256, 0, stream>>>(encb, Wkb, nullptr, kgi, 2048, 1024, 1024);
  else    gemm_f32<0><<<dim3(16, 8), 256, 0, stream>>>(enc,  Wk,  nullptr, kgi, 2048, 1024, 1024);

  attn_ctx<<<16, 256, 0, stream>>>(q_, kgi, wv, vlens, enc, ctx);
  build_x0<<<1024, 256, 0, stream>>>(ctx, emb, inputs, x0f, t2 ? x0b : nullptr);

  // layer 0
  if (t2) gemm_b16<0><<<dim3(8, 24), 256, 0, stream>>>(x0b, Wih0b, b_ih0, kgi, 1024, 3072, 1536);
  else    gemm_f32<0><<<dim3(8, 24), 256, 0, stream>>>(x0f, W_ih0, b_ih0, kgi, 1024, 3072, 1536);
  gru_combine<<<4096, 256, 0, stream>>>(kgi, gh0, ehs0, h1, t2 ? h1b : nullptr);

  // layer 1 (h2 -> d_ws; it must survive the logits C-write)
  if (t2) gemm_b16<0><<<dim3(8, 24), 256, 0, stream>>>(h1b, Wih1b, b_ih1, kgi, 1024, 3072, 1024);
  else    gemm_f32<0><<<dim3(8, 24), 256, 0, stream>>>(h1,  W_ih1, b_ih1, kgi, 1024, 3072, 1024);
  gru_combine<<<4096, 256, 0, stream>>>(kgi, gh1, ehs1, h2, t1 ? h2b : nullptr);

  // decoder_hidden tail BEFORE logits overwrite h1's scratch slot
  write_dh<<<128, 256, 0, stream>>>(h1, h2, out);

  // logits = h2 @ fc_w.T + fc_b  (overwrites the whole scratch arena #1)
  if (t1) gemm_b16<1><<<dim3(8, 250), 256, 0, stream>>>(h2b, fcwb, fc_b, out, 1024, 32000, 1024);
  else    gemm_f32<1><<<dim3(8, 250), 256, 0, stream>>>(h2,  fc_w, fc_b, out, 1024, 32000, 1024);
}

// Round 6
// 648.381 us; speedup vs baseline: 1.3650x; 1.3650x over previous
//
#include <hip/hip_runtime.h>
#include <hip/hip_bf16.h>
#include <cstdint>
#include <cstddef>

typedef __bf16 bf16_t;
typedef __attribute__((ext_vector_type(8))) bf16_t bf16x8;
typedef __attribute__((ext_vector_type(4))) float f32x4;

#define B_   16
#define SDEC 64
#define SENC 128
#define H_   1024
#define E_   512
#define V_   32000

// async global->LDS, 16B per lane. LDS dest = wave-uniform base + lane*16.
__device__ __forceinline__ void gload_lds16(const void* g, void* l) {
  __builtin_amdgcn_global_load_lds(
      (const __attribute__((address_space(1))) unsigned int*)g,
      (__attribute__((address_space(3))) unsigned int*)l, 16, 0, 0);
}

// ---------------------------------------------------------------------------
// f32 -> bf16 cast, 8 elems/thread.
// ---------------------------------------------------------------------------
__global__ __launch_bounds__(256)
void cvt_bf16(const float* __restrict__ s, bf16_t* __restrict__ d, int n8)
{
  const int i = blockIdx.x * 256 + threadIdx.x;
  if (i >= n8) return;
  const f32x4* sp = (const f32x4*)s + (size_t)i * 2;
  f32x4 a = sp[0], b = sp[1];
  union { bf16_t h[8]; uint4 u; } p;
  p.h[0] = (bf16_t)a[0]; p.h[1] = (bf16_t)a[1];
  p.h[2] = (bf16_t)a[2]; p.h[3] = (bf16_t)a[3];
  p.h[4] = (bf16_t)b[0]; p.h[5] = (bf16_t)b[1];
  p.h[6] = (bf16_t)b[2]; p.h[7] = (bf16_t)b[3];
  *(uint4*)(d + (size_t)i * 8) = p.u;
}

// ---------------------------------------------------------------------------
// m97-structure bf16 GEMM: C[M,N] = A[M,K] @ W[N,K]^T (+bias), f32 out.
// 128x128 tile, BK=64, 4 waves, global_load_lds w16, 16x16x32 bf16 MFMA.
// Requires M%128==0, N%128==0, K%64==0, grid=(M/128, N/128), nwg%8==0.
// MODE 0: C[m*N+n]   MODE 1: m=s*16+b -> C[(b*64+s)*V_+n]
// ---------------------------------------------------------------------------
template<int MODE>
__global__ __launch_bounds__(256)
void gemm_b16(const bf16_t* __restrict__ A, const bf16_t* __restrict__ W,
              const float* __restrict__ bias, float* __restrict__ C,
              int M, int N, int K)
{
  __shared__ __align__(16) char lsA[128 * 128];  // 128 rows x 64 bf16
  __shared__ __align__(16) char lsB[128 * 128];

  const int t = threadIdx.x, lane = t & 63, wid = t >> 6;
  const int wr = wid >> 1, wc = wid & 1;

  const int nwg = gridDim.x * gridDim.y;
  const int dd  = blockIdx.y * gridDim.x + blockIdx.x;
  const int qq  = nwg >> 3;
  const int lid = (dd & 7) * qq + (dd >> 3);
  const int mt  = lid % gridDim.x;      // m fastest -> W n-panel stays in L2
  const int nt  = lid / gridDim.x;
  const int m0 = mt * 128, n0 = nt * 128;

  const int srow = wid * 32 + (lane >> 3);
  const int scol = (lane & 7) * 8;               // bf16 elems
  const bf16_t* agp = A + (size_t)(m0 + srow) * K + scol;
  const bf16_t* wgp = W + (size_t)(n0 + srow) * K + scol;
  char* alds = lsA + wid * 32 * 128;
  char* wlds = lsB + wid * 32 * 128;

  f32x4 acc[4][4] = {};

  for (int k0 = 0; k0 < K; k0 += 64) {
#pragma unroll
    for (int i = 0; i < 4; ++i)
      gload_lds16(agp + (size_t)(i * 8) * K + k0, alds + i * 1024);
#pragma unroll
    for (int i = 0; i < 4; ++i)
      gload_lds16(wgp + (size_t)(i * 8) * K + k0, wlds + i * 1024);
    __syncthreads();

#pragma unroll
    for (int kk = 0; kk < 2; ++kk) {
      bf16x8 af[4], bfr[4];
      const int cb = kk * 64 + ((lane >> 4) << 4);
#pragma unroll
      for (int mi = 0; mi < 4; ++mi)
        af[mi] = *(const bf16x8*)(lsA + (wr * 64 + mi * 16 + (lane & 15)) * 128 + cb);
#pragma unroll
      for (int ni = 0; ni < 4; ++ni)
        bfr[ni] = *(const bf16x8*)(lsB + (wc * 64 + ni * 16 + (lane & 15)) * 128 + cb);
#pragma unroll
      for (int mi = 0; mi < 4; ++mi)
#pragma unroll
        for (int ni = 0; ni < 4; ++ni)
          acc[mi][ni] = __builtin_amdgcn_mfma_f32_16x16x32_bf16(
              af[mi], bfr[ni], acc[mi][ni], 0, 0, 0);
    }
    __syncthreads();
  }

  // C/D layout: col=lane&15, row=(lane>>4)*4+j
#pragma unroll
  for (int mi = 0; mi < 4; ++mi) {
#pragma unroll
    for (int ni = 0; ni < 4; ++ni) {
      const int n = n0 + wc * 64 + ni * 16 + (lane & 15);
      const float bv = bias ? bias[n] : 0.f;
#pragma unroll
      for (int j = 0; j < 4; ++j) {
        const int m = m0 + wr * 64 + mi * 16 + ((lane >> 4) << 2) + j;
        const float v = acc[mi][ni][j] + bv;
        if (MODE == 0) {
          C[(size_t)m * N + n] = v;
        } else {
          const int s = m >> 4, b = m & 15;
          C[((size_t)b * SDEC + s) * V_ + n] = v;
        }
      }
    }
  }
}

// ---------------------------------------------------------------------------
// f32-staged fallback GEMM (in-flight bf16 convert, swizzled LDS).
// ---------------------------------------------------------------------------
template<int MODE>
__global__ __launch_bounds__(256)
void gemm_f32(const float* __restrict__ A, const float* __restrict__ W,
              const float* __restrict__ bias, float* __restrict__ C,
              int M, int N, int K)
{
  __shared__ __align__(16) char lsA[128 * 128];
  __shared__ __align__(16) char lsB[128 * 128];

  const int t = threadIdx.x, lane = t & 63, wid = t >> 6;
  const int wr = wid >> 1, wc = wid & 1;

  const int nwg = gridDim.x * gridDim.y;
  const int dd  = blockIdx.y * gridDim.x + blockIdx.x;
  const int qq  = nwg >> 3;
  const int lid = (dd & 7) * qq + (dd >> 3);
  const int mt  = lid % gridDim.x;
  const int nt  = lid / gridDim.x;
  const int m0 = mt * 128, n0 = nt * 128;

  const int rg = t >> 4, c4 = t & 15;
  f32x4 acc[4][4] = {};

  for (int k0 = 0; k0 < K; k0 += 64) {
    const float* ap = A + (size_t)(m0 + rg * 8) * K + k0 + c4 * 4;
    const float* bp = W + (size_t)(n0 + rg * 8) * K + k0 + c4 * 4;
#pragma unroll
    for (int i = 0; i < 8; ++i) {
      f32x4 va = *(const f32x4*)(ap + (size_t)i * K);
      f32x4 vb = *(const f32x4*)(bp + (size_t)i * K);
      const int row  = rg * 8 + i;
      const int boff = row * 128 + ((c4 * 8) ^ ((row & 7) << 4));
      union { bf16_t h[4]; uint2 u; } pa, pb;
      pa.h[0] = (bf16_t)va[0]; pa.h[1] = (bf16_t)va[1];
      pa.h[2] = (bf16_t)va[2]; pa.h[3] = (bf16_t)va[3];
      pb.h[0] = (bf16_t)vb[0]; pb.h[1] = (bf16_t)vb[1];
      pb.h[2] = (bf16_t)vb[2]; pb.h[3] = (bf16_t)vb[3];
      *(uint2*)(lsA + boff) = pa.u;
      *(uint2*)(lsB + boff) = pb.u;
    }
    __syncthreads();
#pragma unroll
    for (int kk = 0; kk < 2; ++kk) {
      bf16x8 af[4], bfr[4];
#pragma unroll
      for (int mi = 0; mi < 4; ++mi) {
        const int r  = wr * 64 + mi * 16 + (lane & 15);
        const int bc = (kk * 64 + ((lane >> 4) << 4)) ^ ((r & 7) << 4);
        af[mi] = *(const bf16x8*)(lsA + r * 128 + bc);
      }
#pragma unroll
      for (int ni = 0; ni < 4; ++ni) {
        const int r  = wc * 64 + ni * 16 + (lane & 15);
        const int bc = (kk * 64 + ((lane >> 4) << 4)) ^ ((r & 7) << 4);
        bfr[ni] = *(const bf16x8*)(lsB + r * 128 + bc);
      }
#pragma unroll
      for (int mi = 0; mi < 4; ++mi)
#pragma unroll
        for (int ni = 0; ni < 4; ++ni)
          acc[mi][ni] = __builtin_amdgcn_mfma_f32_16x16x32_bf16(
              af[mi], bfr[ni], acc[mi][ni], 0, 0, 0);
    }
    __syncthreads();
  }

#pragma unroll
  for (int mi = 0; mi < 4; ++mi) {
#pragma unroll
    for (int ni = 0; ni < 4; ++ni) {
      const int n = n0 + wc * 64 + ni * 16 + (lane & 15);
      const float bv = bias ? bias[n] : 0.f;
#pragma unroll
      for (int j = 0; j < 4; ++j) {
        const int m = m0 + wr * 64 + mi * 16 + ((lane >> 4) << 2) + j;
        const float v = acc[mi][ni][j] + bv;
        if (MODE == 0) {
          C[(size_t)m * N + n] = v;
        } else {
          const int s = m >> 4, b = m & 15;
          C[((size_t)b * SDEC + s) * V_ + n] = v;
        }
      }
    }
  }
}

// ---------------------------------------------------------------------------
// Small-M GEMM: out[16,N] = X[16,K] @ W[N,K]^T (+bias). One wave per n.
// No LDS (X is 64KB, shared by all blocks -> L1/L2-resident), f32x4 loads.
// K % 256 == 0. grid = N/4 blocks of 256 threads.
// ---------------------------------------------------------------------------
__global__ __launch_bounds__(256)
void small_bt(const float* __restrict__ X, const float* __restrict__ W,
              const float* __restrict__ bias, float* __restrict__ out,
              int N, int K)
{
  const int t = threadIdx.x, lane = t & 63;
  const int n = blockIdx.x * 4 + (t >> 6);
  float acc[16];
#pragma unroll
  for (int b = 0; b < 16; ++b) acc[b] = 0.f;
  const float* wrow = W + (size_t)n * K;
  for (int kc = 0; kc < K; kc += 256) {
    const f32x4 w4 = *(const f32x4*)(wrow + kc + lane * 4);
#pragma unroll
    for (int b = 0; b < 16; ++b) {
      const f32x4 x4 = *(const f32x4*)(X + b * K + kc + lane * 4);
      acc[b] += w4[0] * x4[0] + w4[1] * x4[1] + w4[2] * x4[2] + w4[3] * x4[3];
    }
  }
  const float bv = bias ? bias[n] : 0.f;
#pragma unroll
  for (int b = 0; b < 16; ++b) {
    float v = acc[b];
#pragma unroll
    for (int o = 32; o; o >>= 1) v += __shfl_xor(v, o);
    if (lane == b) out[(size_t)b * N + n] = v + bv;
  }
}

// ---------------------------------------------------------------------------
// Attention part 1: scores[b,s] = tanh(q[b]+k[b,s]) . wv  (masked).
// grid (32,16): one wave per (b, s). 512 blocks.
// ---------------------------------------------------------------------------
__global__ __launch_bounds__(256)
void attn_scores(const float* __restrict__ q, const float* __restrict__ kproj,
                 const float* __restrict__ wv, const int* __restrict__ vlens,
                 float* __restrict__ sc_g)
{
  const int b = blockIdx.y;
  const int t = threadIdx.x, lane = t & 63, wid = t >> 6;
  const int s = blockIdx.x * 4 + wid;
  const float* kp = kproj + ((size_t)b * SENC + s) * H_;
  const float* qp = q + b * H_;
  float a = 0.f;
#pragma unroll
  for (int i = 0; i < 4; ++i) {
    const int h = i * 256 + lane * 4;
    const f32x4 qv = *(const f32x4*)(qp + h);
    const f32x4 kv = *(const f32x4*)(kp + h);
    const f32x4 wvv = *(const f32x4*)(wv + h);
#pragma unroll
    for (int j = 0; j < 4; ++j)
      a += tanhf(qv[j] + kv[j]) * wvv[j];
  }
#pragma unroll
  for (int o = 32; o; o >>= 1) a += __shfl_xor(a, o);
  if (lane == 0) sc_g[b * SENC + s] = (s < vlens[b]) ? a : -1e6f;
}

// ---------------------------------------------------------------------------
// Attention part 2: softmax over s (redundant per block) + context gather.
// grid (8,16): block (hg, b), 128 threads; each block covers 128 h-columns.
// ---------------------------------------------------------------------------
__global__ __launch_bounds__(128)
void attn_sm_ctx(const float* __restrict__ sc_g, const float* __restrict__ enc,
                 float* __restrict__ context)
{
  __shared__ float at[SENC];
  __shared__ float redm[2], reds[2];
  const int b = blockIdx.y, hg = blockIdx.x;
  const int t = threadIdx.x;

  const float s0 = sc_g[b * SENC + t];
  float m = s0;
#pragma unroll
  for (int o = 32; o; o >>= 1) m = fmaxf(m, __shfl_xor(m, o));
  if ((t & 63) == 0) redm[t >> 6] = m;
  __syncthreads();
  m = fmaxf(redm[0], redm[1]);
  const float e = expf(s0 - m);
  float sum = e;
#pragma unroll
  for (int o = 32; o; o >>= 1) sum += __shfl_xor(sum, o);
  if ((t & 63) == 0) reds[t >> 6] = sum;
  __syncthreads();
  at[t] = e / (reds[0] + reds[1]);
  __syncthreads();

  const int h = hg * 128 + t;
  const float* ep = enc + (size_t)b * SENC * H_ + h;
  float a = 0.f;
#pragma unroll 8
  for (int s = 0; s < SENC; ++s)
    a += at[s] * ep[(size_t)s * H_];
  context[b * H_ + h] = a;
}

// x0[m,0:1024]=context[b], x0[m,1024:1536]=emb[inputs[b,s]]  (m = s*16+b)
__global__ __launch_bounds__(256)
void build_x0(const float* __restrict__ context, const float* __restrict__ emb,
              const int* __restrict__ inputs, float* __restrict__ x0f,
              bf16_t* __restrict__ x0b)
{
  const int m = blockIdx.x;
  const int b = m & 15, s = m >> 4;
  const int t = threadIdx.x;
  float* xr = x0f + (size_t)m * 1536;
  bf16_t* xb = x0b ? x0b + (size_t)m * 1536 : nullptr;
  const float* er = emb + (size_t)inputs[b * 64 + s] * 512;
  for (int j = t; j < 1024; j += 256) {
    const float v = context[b * 1024 + j];
    xr[j] = v; if (xb) xb[j] = (bf16_t)v;
  }
  for (int j = t; j < 512; j += 256) {
    const float v = er[j];
    xr[1024 + j] = v; if (xb) xb[1024 + j] = (bf16_t)v;
  }
}

// GRU gate combine -> hout (f32) and optional bf16 copy for the next GEMM.
__global__ __launch_bounds__(256)
void gru_combine(const float* __restrict__ gi, const float* __restrict__ gh,
                 const float* __restrict__ hprev, float* __restrict__ hout,
                 bf16_t* __restrict__ houtb)
{
  const int idx = blockIdx.x * 256 + threadIdx.x;
  const int m = idx >> 10, j = idx & 1023, b = m & 15;
  const float* gim = gi + (size_t)m * 3072;
  const float* ghb = gh + (size_t)b * 3072;
  const float ir = gim[j], iz = gim[1024 + j], in_ = gim[2048 + j];
  const float hr = ghb[j], hz = ghb[1024 + j], hn = ghb[2048 + j];
  const float r = 1.f / (1.f + expf(-(ir + hr)));
  const float z = 1.f / (1.f + expf(-(iz + hz)));
  const float n = tanhf(in_ + r * hn);
  const float v = (1.f - z) * n + z * hprev[b * 1024 + j];
  hout[idx] = v;
  if (houtb) houtb[idx] = (bf16_t)v;
}

// decoder_hidden = stack([h1[step 63], h2[step 63]]) -> out tail.
// MUST run before the logits GEMM (h1 lives in the logits scratch region).
__global__ __launch_bounds__(256)
void write_dh(const float* __restrict__ h1, const float* __restrict__ h2,
              float* __restrict__ out)
{
  const int idx = blockIdx.x * 256 + threadIdx.x;  // 0..32767
  const int l = idx >> 14;
  const int b = (idx >> 10) & 15;
  const int h = idx & 1023;
  const float* src = l ? h2 : h1;
  out[(size_t)B_ * SDEC * V_ + idx] = src[(size_t)(63 * 16 + b) * 1024 + h];
}

// ---------------------------------------------------------------------------
extern "C" void kernel_launch(void* const* d_in, const int* in_sizes, int n_in,
                              void* d_out, int out_size, void* d_ws, size_t ws_size,
                              hipStream_t stream)
{
  const int*   inputs = (const int*)  d_in[0];
  const float* enc    = (const float*)d_in[1];
  const float* ehs    = (const float*)d_in[2];
  const int*   vlens  = (const int*)  d_in[3];
  const float* emb    = (const float*)d_in[4];
  const float* Wq     = (const float*)d_in[5];
  const float* Wk     = (const float*)d_in[6];
  const float* wv     = (const float*)d_in[7];
  const float* W_ih0  = (const float*)d_in[8];
  const float* W_hh0  = (const float*)d_in[9];
  const float* b_ih0  = (const float*)d_in[10];
  const float* b_hh0  = (const float*)d_in[11];
  const float* W_ih1  = (const float*)d_in[12];
  const float* W_hh1  = (const float*)d_in[13];
  const float* b_ih1  = (const float*)d_in[14];
  const float* b_hh1  = (const float*)d_in[15];
  const float* fc_w   = (const float*)d_in[16];
  const float* fc_b   = (const float*)d_in[17];
  float* out = (float*)d_out;

  // ---- scratch arena #1: the logits region of d_out (131 MB, re-poisoned
  // each launch; everything here is dead before the logits GEMM overwrites
  // it). Offsets in f32 units. ----
  float*  kgi  = out;                        // 3,145,728 (kproj / gi)
  float*  x0f  = out + 3145728;              // 1,572,864
  bf16_t* x0b  = (bf16_t*)(out + 4718592);   //   786,432 f32 slots
  float*  h1   = out + 5505024;              // 1,048,576
  bf16_t* h1b  = (bf16_t*)(out + 6553600);   //   524,288 f32 slots
  float*  q_   = out + 7077888;              //    16,384
  float*  ctx  = out + 7094272;              //    16,384
  float*  gh0  = out + 7110656;              //    49,152
  float*  gh1  = out + 7159808;              //    49,152
  float*  scg  = out + 7208960;              //     2,048 (scores)

  // ---- scratch arena #2: d_ws, tier-guarded. Only h2 (4 MB) required. ----
  float*  ws    = (float*)d_ws;
  float*  h2    = ws;                        // 1,048,576 f32 = 4 MB (required)
  bf16_t* h2b   = (bf16_t*)(ws + 1048576);   // 524,288 f32 slots
  bf16_t* encb  = (bf16_t*)(ws + 1572864);   // 1,048,576 f32 slots
  bf16_t* Wkb   = (bf16_t*)(ws + 2621440);   //   524,288
  bf16_t* Wih0b = (bf16_t*)(ws + 3145728);   // 2,359,296
  bf16_t* Wih1b = (bf16_t*)(ws + 5505024);   // 1,572,864 -> t2 end 7,077,888
  bf16_t* fcwb  = (bf16_t*)(ws + 7077888);   // 16,384,000 -> t1 end 23,461,888

  const bool hb = ws_size >= (size_t)1572864  * 4;
  const bool t2 = ws_size >= (size_t)7077888  * 4;
  const bool t1 = ws_size >= (size_t)23461888 * 4 && hb;

  const float* ehs0 = ehs;
  const float* ehs1 = ehs + 16 * 1024;

  // weight conversions (tier-guarded, all into d_ws)
  if (t2) {
    cvt_bf16<<<512,  256, 0, stream>>>(Wk,    Wkb,   1048576 / 8);
    cvt_bf16<<<2304, 256, 0, stream>>>(W_ih0, Wih0b, 4718592 / 8);
    cvt_bf16<<<1536, 256, 0, stream>>>(W_ih1, Wih1b, 3145728 / 8);
    cvt_bf16<<<1024, 256, 0, stream>>>(enc,   encb,  2097152 / 8);
  }
  if (t1)
    cvt_bf16<<<16000, 256, 0, stream>>>(fc_w, fcwb, 32768000 / 8);

  // q = ehs[1] @ Wq.T ; gh_l = ehs[l] @ W_hh_l.T + b_hh_l
  small_bt<<<256, 256, 0, stream>>>(ehs1, Wq, nullptr, q_, 1024, 1024);
  small_bt<<<768, 256, 0, stream>>>(ehs0, W_hh0, b_hh0, gh0, 3072, 1024);
  small_bt<<<768, 256, 0, stream>>>(ehs1, W_hh1, b_hh1, gh1, 3072, 1024);

  // kproj = enc @ Wk.T  [2048,1024]
  if (t2) gemm_b16<0><<<dim3(16, 8), 256, 0, stream>>>(encb, Wkb, nullptr, kgi, 2048, 1024, 1024);
  else    gemm_f32<0><<<dim3(16, 8), 256, 0, stream>>>(enc,  Wk,  nullptr, kgi, 2048, 1024, 1024);

  // attention -> context (two-stage, machine-wide)
  attn_scores<<<dim3(32, 16), 256, 0, stream>>>(q_, kgi, wv, vlens, scg);
  attn_sm_ctx<<<dim3(8, 16), 128, 0, stream>>>(scg, enc, ctx);

  build_x0<<<1024, 256, 0, stream>>>(ctx, emb, inputs, x0f, t2 ? x0b : nullptr);

  // layer 0
  if (t2) gemm_b16<0><<<dim3(8, 24), 256, 0, stream>>>(x0b, Wih0b, b_ih0, kgi, 1024, 3072, 1536);
  else    gemm_f32<0><<<dim3(8, 24), 256, 0, stream>>>(x0f, W_ih0, b_ih0, kgi, 1024, 3072, 1536);
  gru_combine<<<4096, 256, 0, stream>>>(kgi, gh0, ehs0, h1, t2 ? h1b : nullptr);

  // layer 1 (h2 -> d_ws; must survive the logits C-write)
  if (t2) gemm_b16<0><<<dim3(8, 24), 256, 0, stream>>>(h1b, Wih1b, b_ih1, kgi, 1024, 3072, 1024);
  else    gemm_f32<0><<<dim3(8, 24), 256, 0, stream>>>(h1,  W_ih1, b_ih1, kgi, 1024, 3072, 1024);
  gru_combine<<<4096, 256, 0, stream>>>(kgi, gh1, ehs1, h2, t1 ? h2b : nullptr);

  // decoder_hidden tail BEFORE logits overwrite h1's scratch slot
  write_dh<<<128, 256, 0, stream>>>(h1, h2, out);

  // logits = h2 @ fc_w.T + fc_b  (overwrites the whole scratch arena #1)
  if (t1) gemm_b16<1><<<dim3(8, 250), 256, 0, stream>>>(h2b, fcwb, fc_b, out, 1024, 32000, 1024);
  else    gemm_f32<1><<<dim3(8, 250), 256, 0, stream>>>(h2,  fc_w, fc_b, out, 1024, 32000, 1024);
}